// Round 8
// baseline (45.346 us; speedup 1.0000x reference)
//
#include <hip/hip_runtime.h>
#include <hip/hip_bf16.h>
#include <math.h>

#define D_MODEL 512
#define N_PEAKS 500
#define BATCH   1024
#define BLOCK   256
#define SPLIT   2
#define NPB     (N_PEAKS / SPLIT)   // 250 peaks per block
#define TBITS   11
#define TSIZE   (1 << TBITS)        // 2048-entry cis table, 16 KB LDS

// out[b][2k]   = sum_n w * sin(idx * omega_k)
// out[b][2k+1] = sum_n w * cos(idx * omega_k)
// idx = ceil(loc*10); omega_k = exp(2k * -ln(1e4)/512); pe row 0 zeroed ->
// mask idx==0 peaks.
//
// R8 (from R7 counters): LDS cis-table lookup, but with R7's three taxes
// removed:
//  1. angle math in float: j = ((uint)(idx * (wk_rev*2048))) & 2047
//     -> v_mul_f32 + v_cvt_u32_f32 + v_and (full-rate) instead of
//     quarter-rate v_mul_lo_u32 + shifts.
//  2. 16KB table + 2KB peaks (SPLIT=2) = 18.4KB LDS -> 8 blocks/CU,
//     8 waves/SIMD: hides the ~120cyc conflicted gather latency that R7's
//     2.65 waves/SIMD exposed.
//  3. table fill via native v_sin/v_cos in revolutions (no ocml).
// Partials combined with two deterministic f32 atomic adds per element
// (2-operand commutative add; validated R4/R5).
__global__ __launch_bounds__(BLOCK)
void SpectrumEncoding_84164179132426_kernel(const float* __restrict__ loc,
                                            const float* __restrict__ inten,
                                            float* __restrict__ out) {
    __shared__ float2 s_cis[TSIZE];   // (sin, cos) of 2*pi*j/TSIZE
    __shared__ float2 s_iw[NPB];      // {idx as float, masked weight}

    const int b    = blockIdx.x >> 1;
    const int half = blockIdx.x & 1;
    const int t    = threadIdx.x;

    // Fill cis table: 8 entries/thread, native trans in revolutions.
    const float inv = 1.0f / (float)TSIZE;
#pragma unroll
    for (int j = t; j < TSIZE; j += BLOCK) {
        float r = (float)j * inv;                    // [0,1) revolutions
        s_cis[j] = make_float2(__builtin_amdgcn_sinf(r),
                               __builtin_amdgcn_cosf(r));
    }

    // Stage this half's peaks.
    const int base = b * N_PEAKS + half * NPB;
    if (t < NPB) {
        float l    = loc[base + t];
        float idxf = ceilf(l * 10.0f);               // matches jnp.ceil(loc*10)
        float w    = inten[base + t];
        s_iw[t] = make_float2(idxf, (idxf == 0.0f) ? 0.0f : w);
    }
    __syncthreads();

    // wk2048 = frac-domain frequency * table size; f64 once for precision.
    const double cd = -log(10000.0) / (double)D_MODEL;
    const float wk2048 =
        (float)(exp((double)(2 * t) * cd) / (2.0 * M_PI) * (double)TSIZE);

    float acc_s = 0.0f, acc_c = 0.0f;

#pragma unroll 4
    for (int n = 0; n < NPB; ++n) {
        const float2 iw = s_iw[n];                   // broadcast ds_read_b64
        const float  x  = iw.x * wk2048;             // idx * wk * 2048 (< 2^24 ok)
        const unsigned int j = (unsigned int)x & (TSIZE - 1);
        const float2 sc = s_cis[j];                  // gathered ds_read_b64
        acc_s = fmaf(iw.y, sc.x, acc_s);
        acc_c = fmaf(iw.y, sc.y, acc_c);
    }

    float* o = out + b * D_MODEL + 2 * t;
    unsafeAtomicAdd(o,     acc_s);                   // 2 deterministic f32 addends
    unsafeAtomicAdd(o + 1, acc_c);
}

extern "C" void kernel_launch(void* const* d_in, const int* in_sizes, int n_in,
                              void* d_out, int out_size, void* d_ws, size_t ws_size,
                              hipStream_t stream) {
    const float* loc   = (const float*)d_in[0];   // [1024, 500] f32
    const float* inten = (const float*)d_in[1];   // [1024, 500] f32
    // d_in[2] (pe table) intentionally unused: recomputed analytically.
    float*       out   = (float*)d_out;           // [1024, 512] f32

    hipMemsetAsync(d_out, 0, (size_t)BATCH * D_MODEL * sizeof(float), stream);
    SpectrumEncoding_84164179132426_kernel<<<BATCH * SPLIT, BLOCK, 0, stream>>>(loc, inten, out);
}

// Round 9
// 44.520 us; speedup vs baseline: 1.0186x; 1.0186x over previous
//
#include <hip/hip_runtime.h>
#include <hip/hip_bf16.h>
#include <hip/hip_fp16.h>
#include <math.h>

#define D_MODEL 512
#define N_PEAKS 500
#define BATCH   1024
#define BLOCK   256
#define SPLIT   2
#define NPB     (N_PEAKS / SPLIT)   // 250 real peaks per block
#define NPAD    256                 // padded to 256 (zero weight) -> uniform loop
#define TBITS   11
#define TSIZE   (1 << TBITS)        // 2048-entry cis table

// out[b][2k]   = sum_n w * sin(idx * omega_k)
// out[b][2k+1] = sum_n w * cos(idx * omega_k)
// idx = ceil(loc*10); omega_k = exp(2k * -ln(1e4)/512); pe row 0 zeroed.
//
// R9 (from R8 counters: LDS pipe 73% with b64 random gather, loop
// latency-exposed):
//  - cis table stored as __half2 (8 KB): gather is ds_read_b32, one bank per
//    lane -> conflict serialization ~5 cyc instead of ~8.
//  - manual 4-wide unroll, all 4 gathers issued before any use (4-deep MLP).
//  - peaks padded to 256 with w=0 -> branch-free uniform 64-group loop; the
//    (idx,w) pairs arrive via two b128 same-address broadcasts per group.
//  - SPLIT=2 + in-stream memset + two deterministic f32 atomic adds/elem.
__global__ __launch_bounds__(BLOCK, 8)
void SpectrumEncoding_84164179132426_kernel(const float* __restrict__ loc,
                                            const float* __restrict__ inten,
                                            float* __restrict__ out) {
    __shared__ __half2 s_cis[TSIZE];          // {sin, cos}(2*pi*j/TSIZE), f16
    __shared__ __align__(16) float2 s_iw[NPAD];  // {idxf, masked w}, zero-padded

    const int b    = blockIdx.x >> 1;
    const int half = blockIdx.x & 1;
    const int t    = threadIdx.x;

    // Fill cis table: 8 entries/thread, native trans in revolutions (exact args).
    const float inv = 1.0f / (float)TSIZE;
#pragma unroll
    for (int j = t; j < TSIZE; j += BLOCK) {
        float r = (float)j * inv;             // [0,1) revolutions, exact
        s_cis[j] = __floats2half2_rn(__builtin_amdgcn_sinf(r),
                                     __builtin_amdgcn_cosf(r));
    }

    // Stage this half's peaks; pad 250..255 with zero weight.
    const int base = b * N_PEAKS + half * NPB;
    {
        float idxf = 0.0f, w = 0.0f;
        if (t < NPB) {
            float l = loc[base + t];
            idxf = ceilf(l * 10.0f);          // matches jnp.ceil(loc*10)
            w    = inten[base + t];
            if (idxf == 0.0f) w = 0.0f;       // reference pe row 0 is zeroed
        }
        s_iw[t] = make_float2(idxf, w);
    }
    __syncthreads();

    // wk = frac-domain frequency * TSIZE, f64 once per thread.
    const double cd = -log(10000.0) / (double)D_MODEL;
    const float wk =
        (float)(exp((double)(2 * t) * cd) / (2.0 * M_PI) * (double)TSIZE);

    float as0 = 0.f, ac0 = 0.f, as1 = 0.f, ac1 = 0.f;

    const float4* P = (const float4*)s_iw;    // 128 float4 = 256 (idx,w) pairs

#pragma unroll 2
    for (int g = 0; g < NPAD / 4; ++g) {
        const float4 a = P[2 * g];            // peaks 4g, 4g+1 (broadcast b128)
        const float4 c = P[2 * g + 1];        // peaks 4g+2, 4g+3

        // all 4 independent gathers issue before any consumption (MLP x4)
        const unsigned j0 = (unsigned)(a.x * wk) & (TSIZE - 1);
        const unsigned j1 = (unsigned)(a.z * wk) & (TSIZE - 1);
        const unsigned j2 = (unsigned)(c.x * wk) & (TSIZE - 1);
        const unsigned j3 = (unsigned)(c.z * wk) & (TSIZE - 1);
        const __half2 g0 = s_cis[j0];
        const __half2 g1 = s_cis[j1];
        const __half2 g2 = s_cis[j2];
        const __half2 g3 = s_cis[j3];

        as0 = fmaf(a.y, __low2float(g0),  as0);
        ac0 = fmaf(a.y, __high2float(g0), ac0);
        as1 = fmaf(a.w, __low2float(g1),  as1);
        ac1 = fmaf(a.w, __high2float(g1), ac1);
        as0 = fmaf(c.y, __low2float(g2),  as0);
        ac0 = fmaf(c.y, __high2float(g2), ac0);
        as1 = fmaf(c.w, __low2float(g3),  as1);
        ac1 = fmaf(c.w, __high2float(g3), ac1);
    }

    float* o = out + b * D_MODEL + 2 * t;
    unsafeAtomicAdd(o,     as0 + as1);        // 2 deterministic f32 addends
    unsafeAtomicAdd(o + 1, ac0 + ac1);
}

extern "C" void kernel_launch(void* const* d_in, const int* in_sizes, int n_in,
                              void* d_out, int out_size, void* d_ws, size_t ws_size,
                              hipStream_t stream) {
    const float* loc   = (const float*)d_in[0];   // [1024, 500] f32
    const float* inten = (const float*)d_in[1];   // [1024, 500] f32
    // d_in[2] (pe table) intentionally unused: recomputed analytically.
    float*       out   = (float*)d_out;           // [1024, 512] f32

    hipMemsetAsync(d_out, 0, (size_t)BATCH * D_MODEL * sizeof(float), stream);
    SpectrumEncoding_84164179132426_kernel<<<BATCH * SPLIT, BLOCK, 0, stream>>>(loc, inten, out);
}

// Round 10
// 41.105 us; speedup vs baseline: 1.1032x; 1.0831x over previous
//
#include <hip/hip_runtime.h>
#include <hip/hip_bf16.h>
#include <hip/hip_fp16.h>
#include <math.h>

#define D_MODEL 512
#define N_PEAKS 500
#define BATCH   1024
#define BLOCK   256
#define SPLIT   2
#define NPB     (N_PEAKS / SPLIT)   // 250 real peaks per block
#define NPAD    256                 // padded (w=0) -> uniform groups of 4
#define TBITS   11
#define TSIZE   (1 << TBITS)        // 2048-entry f16 cis table, 8 KB

// out[b][2k]   = sum_n w * sin(idx * omega_k)
// out[b][2k+1] = sum_n w * cos(idx * omega_k)
// idx = ceil(loc*10); omega_k = exp(2k*-ln(1e4)/512); pe row 0 zeroed.
//
// R10 — HETEROGENEOUS DUAL-PIPE. Nine rounds established two separate
// hardware floors:
//   trans path: 2 x v_sin(16cyc/wave) per peak -> trans pipe 27us (R3/R4)
//   table path: LDS random gather ~7cyc/wave    -> LDS pipe  23us (R7-R9)
// The pipes are independent; waves drive both concurrently. So: per group of
// 4 peaks, 2 go through the f16 LDS cis table and 2 through native v_sin
// (cos via sin(f+0.25rev)). Per-pipe load halves -> ~13-15us/pipe balanced.
//   - f16 cis table (8KB), byte-masked index: (uint)(idx*wk4) & 0x1FFC
//     (wk4 folds table scale AND byte scale; & clears frac bits).
//   - SPLIT=2 + in-stream memset + 2 deterministic f32 atomic adds/element
//     (2-operand commutative add -> bitwise reproducible).
__global__ __launch_bounds__(BLOCK, 8)
void SpectrumEncoding_84164179132426_kernel(const float* __restrict__ loc,
                                            const float* __restrict__ inten,
                                            float* __restrict__ out) {
    __shared__ __half2 s_cis[TSIZE];             // {sin,cos}(2*pi*j/TSIZE)
    __shared__ __align__(16) float2 s_iw[NPAD];  // {idxf, masked w}, zero-pad

    const int b    = blockIdx.x >> 1;
    const int half = blockIdx.x & 1;
    const int t    = threadIdx.x;

    // Fill cis table: 8 entries/thread, native trans in revolutions.
    const float inv = 1.0f / (float)TSIZE;
#pragma unroll
    for (int j = t; j < TSIZE; j += BLOCK) {
        float r = (float)j * inv;                // [0,1) revolutions, exact
        s_cis[j] = __floats2half2_rn(__builtin_amdgcn_sinf(r),
                                     __builtin_amdgcn_cosf(r));
    }

    // Stage this half's peaks; pad with zero weight.
    const int base = b * N_PEAKS + half * NPB;
    {
        float idxf = 0.0f, w = 0.0f;
        if (t < NPB) {
            float l = loc[base + t];
            idxf = ceilf(l * 10.0f);             // matches jnp.ceil(loc*10)
            w    = inten[base + t];
            if (idxf == 0.0f) w = 0.0f;          // reference pe row 0 zeroed
        }
        s_iw[t] = make_float2(idxf, w);
    }
    __syncthreads();

    // Per-thread frequency constants, f64 once for table-grade precision.
    const double cd  = -log(10000.0) / (double)D_MODEL;
    const double fkd = exp((double)(2 * t) * cd) / (2.0 * M_PI); // rev/index
    const float  wkr = (float)fkd;                               // trans path
    const float  wk4 = (float)(fkd * (double)(TSIZE * 4));       // table path (byte)

    float as0 = 0.f, ac0 = 0.f;      // table-path accumulators
    float as1 = 0.f, ac1 = 0.f;      // trans-path accumulators

    const float4* P = (const float4*)s_iw;       // 128 float4 = 256 pairs
    const char*   T = (const char*)s_cis;

#pragma unroll 2
    for (int g = 0; g < NPAD / 4; ++g) {
        const float4 a = P[2 * g];               // peaks 4g,4g+1  (broadcast)
        const float4 c = P[2 * g + 1];           // peaks 4g+2,4g+3

        // --- 2 peaks via LDS cis table (LDS pipe) ---
        const unsigned j0 = (unsigned)(a.x * wk4) & ((TSIZE - 1) * 4);
        const unsigned j1 = (unsigned)(a.z * wk4) & ((TSIZE - 1) * 4);
        const __half2 g0 = *(const __half2*)(T + j0);
        const __half2 g1 = *(const __half2*)(T + j1);

        // --- 2 peaks via native v_sin (trans pipe); cos = sin(f + 1/4 rev) ---
        const float rs2 = c.x * wkr;
        const float rc2 = fmaf(c.x, wkr, 0.25f);
        const float rs3 = c.z * wkr;
        const float rc3 = fmaf(c.z, wkr, 0.25f);
        const float s2 = __builtin_amdgcn_sinf(__builtin_amdgcn_fractf(rs2));
        const float c2 = __builtin_amdgcn_sinf(__builtin_amdgcn_fractf(rc2));
        const float s3 = __builtin_amdgcn_sinf(__builtin_amdgcn_fractf(rs3));
        const float c3 = __builtin_amdgcn_sinf(__builtin_amdgcn_fractf(rc3));

        as0 = fmaf(a.y, __low2float(g0),  as0);
        ac0 = fmaf(a.y, __high2float(g0), ac0);
        as0 = fmaf(a.w, __low2float(g1),  as0);
        ac0 = fmaf(a.w, __high2float(g1), ac0);
        as1 = fmaf(c.y, s2, as1);
        ac1 = fmaf(c.y, c2, ac1);
        as1 = fmaf(c.w, s3, as1);
        ac1 = fmaf(c.w, c3, ac1);
    }

    float* o = out + b * D_MODEL + 2 * t;
    unsafeAtomicAdd(o,     as0 + as1);           // 2 deterministic addends
    unsafeAtomicAdd(o + 1, ac0 + ac1);
}

extern "C" void kernel_launch(void* const* d_in, const int* in_sizes, int n_in,
                              void* d_out, int out_size, void* d_ws, size_t ws_size,
                              hipStream_t stream) {
    const float* loc   = (const float*)d_in[0];   // [1024, 500] f32
    const float* inten = (const float*)d_in[1];   // [1024, 500] f32
    // d_in[2] (pe table) intentionally unused: recomputed analytically.
    float*       out   = (float*)d_out;           // [1024, 512] f32

    hipMemsetAsync(d_out, 0, (size_t)BATCH * D_MODEL * sizeof(float), stream);
    SpectrumEncoding_84164179132426_kernel<<<BATCH * SPLIT, BLOCK, 0, stream>>>(loc, inten, out);
}